// Round 6
// baseline (441.423 us; speedup 1.0000x reference)
//
#include <hip/hip_runtime.h>
#include <hip/hip_bf16.h>

#define NB 64
#define H0 224
#define W0 224
#define C1 24
#define C2 48
#define H1 112
#define W1 112
#define H2 56
#define W2 56
#define EPSV 1e-5f

// ws layout (float offsets) — total ~38.6 MB (proven safe)
#define WS_STATS1   0                       // 8 x (24+24)
#define WS_COEF1    384
#define WS_STATS2   432                     // 8 x (48+48)
#define WS_COEF2    1200
#define WS_FEAT     1296                    // 64*48
#define WS_B2       4368                    // 13824 fp16 = 6912 float slots (wave-linear w2 frags)
#define WS_X2       11280                   // fp32, pooled PRE-BN conv2 max, 64*48*56*56
#define X2_ELEMS    (NB*C2*H2*W2)
#define OUT0_ELEMS  (NB*H0*W0)

typedef _Float16 v8h __attribute__((ext_vector_type(8)));   // 8 fp16 (4 VGPRs)
typedef float    v4f __attribute__((ext_vector_type(4)));   // MFMA acc

static __device__ __forceinline__ unsigned int packh2(float a, float b) {
    union { _Float16 h[2]; unsigned int u; } p;
    p.h[0] = (_Float16)a; p.h[1] = (_Float16)b;
    return p.u;
}

// ---------------- K1: conv1 -> per-channel sum/sumsq (BN1 stats), full fp32 ----------------
__global__ __launch_bounds__(256) void k_conv1_stats(
    const float* __restrict__ x, const float* __restrict__ w1, const float* __restrict__ b1,
    float* __restrict__ ws)
{
    float s[C1], q[C1];
#pragma unroll
    for (int c = 0; c < C1; c++) { s[c] = 0.f; q[c] = 0.f; }
    const int NT = gridDim.x * 256;
    const int total = NB * H0 * W0;
    for (int p = blockIdx.x * 256 + threadIdx.x; p < total; p += NT) {
        int b = p / (H0 * W0);
        int r = p % (H0 * W0);
        int y = r / W0;
        int xx = r % W0;
        const float* xb = x + b * (H0 * W0);
        float patch[9];
#pragma unroll
        for (int dy = 0; dy < 3; dy++)
#pragma unroll
            for (int dx = 0; dx < 3; dx++) {
                int yy = y + dy - 1, xc = xx + dx - 1;
                bool ok = (yy >= 0) & (yy < H0) & (xc >= 0) & (xc < W0);
                patch[dy * 3 + dx] = ok ? xb[yy * W0 + xc] : 0.f;
            }
#pragma unroll
        for (int c = 0; c < C1; c++) {
            const float* wp = w1 + c * 9;
            float a = b1[c];
#pragma unroll
            for (int k = 0; k < 9; k++) a = fmaf(patch[k], wp[k], a);
            s[c] += a;
            q[c] = fmaf(a, a, q[c]);
        }
    }
#pragma unroll
    for (int c = 0; c < C1; c++) {
#pragma unroll
        for (int off = 32; off > 0; off >>= 1) {
            s[c] += __shfl_down(s[c], off, 64);
            q[c] += __shfl_down(q[c], off, 64);
        }
    }
    __shared__ float sred[2 * C1];
    if (threadIdx.x < 2 * C1) sred[threadIdx.x] = 0.f;
    __syncthreads();
    if ((threadIdx.x & 63) == 0) {
#pragma unroll
        for (int c = 0; c < C1; c++) {
            atomicAdd(&sred[c], s[c]);
            atomicAdd(&sred[C1 + c], q[c]);
        }
    }
    __syncthreads();
    if (threadIdx.x < 2 * C1) {
        atomicAdd(&ws[WS_STATS1 + (blockIdx.x & 7) * 2 * C1 + threadIdx.x], sred[threadIdx.x]);
    }
}

// ---------------- finalize BN1 coeffs ----------------
__global__ void k_fin1(const float* __restrict__ g, const float* __restrict__ bb, float* __restrict__ ws)
{
    int c = threadIdx.x;
    if (c >= C1) return;
    float s = 0.f, q = 0.f;
    for (int i = 0; i < 8; i++) {
        s += ws[WS_STATS1 + i * 2 * C1 + c];
        q += ws[WS_STATS1 + i * 2 * C1 + C1 + c];
    }
    const float N = (float)(NB * H0 * W0);
    float m = s / N;
    float v = q / N - m * m;
    float a = g[c] / sqrtf(v + EPSV);
    ws[WS_COEF1 + c] = a;
    ws[WS_COEF1 + C1 + c] = bb[c] - m * a;
}

// ---------------- prep: w2 -> wave-linear fp16 fragment layout ----------------
// bpp[(g*64 + lane)*8 + e] where g=kp*3+nt, lane=q*16+ml, holds w2[oc=nt*16+ml][ic=q*8+e][kp]
// (0 for ic>=24). Each wave's fragment read is then lane-linear 16B -> conflict-free.
__global__ void k_prep(const float* __restrict__ w2, _Float16* __restrict__ bpp)
{
    int t = blockIdx.x * 256 + threadIdx.x;
    if (t >= 13824) return;
    int e = t & 7;
    int l = (t >> 3) & 63;
    int g = t >> 9;
    int q = l >> 4, ml = l & 15;
    int kp = g / 3, nt = g % 3;
    int ic = q * 8 + e;
    int oc = nt * 16 + ml;
    float v = (ic < C1) ? w2[(oc * C1 + ic) * 9 + kp] : 0.f;
    bpp[t] = (_Float16)v;
}

// ---------------- Fused single pass: conv1(recompute)+BN1+relu+pool -> conv2 MFMA ----------------
// Emits BN2 stats AND pooled PRE-BN max (a2>0 so maxpool commutes with BN2 affine+relu).
// Tile: 16x16 conv2 outputs. Grid (7, 7, 64).
__global__ __launch_bounds__(256, 2) void k_conv2_fused(
    const float* __restrict__ x, const float* __restrict__ w1, const float* __restrict__ b1,
    const float* __restrict__ coef1, const _Float16* __restrict__ bpp,
    const float* __restrict__ b2,
    float* __restrict__ stats, float* __restrict__ pool)
{
    __shared__ _Float16 xt[38][38];                          // raw x tile, fp16 (2888 B)
    __shared__ __align__(16) _Float16 x1t[18][18][32];       // x1 tile, ch-last, ic pad 32 (20736 B)
    __shared__ __align__(16) _Float16 Blds[13824];           // w2 frags, wave-linear (27648 B)
    __shared__ float wlds[C1 * 9];
    __shared__ float blds[C1], alds[C1], bflds[C1];
    __shared__ float sred[2 * C2];

    const int tid = threadIdx.x;
    const int b = blockIdx.z;
    const int y0 = blockIdx.y * 16;
    const int x0 = blockIdx.x * 16;
    const float* xb = x + b * (H0 * W0);

    // stage B fragments (completes before MFMA phase; latency hidden under conv1)
    for (int li = tid; li < 13824 / 8; li += 256)
        ((uint4*)Blds)[li] = ((const uint4*)bpp)[li];

    if (tid < C1 * 9) wlds[tid] = w1[tid];
    if (tid < C1) { blds[tid] = b1[tid]; alds[tid] = coef1[tid]; bflds[tid] = coef1[C1 + tid]; }
    if (tid < 2 * C2) sred[tid] = 0.f;

    // stage raw x tile as fp16 pairs: rows 2*y0-3 .. +34, cols same (38x38)
    const int oy0 = 2 * y0 - 3, ox0 = 2 * x0 - 3;
    for (int li = tid; li < 38 * 19; li += 256) {
        int ry = li / 19, rx = (li % 19) * 2;
        int gy = oy0 + ry;
        int gx0 = ox0 + rx, gx1 = gx0 + 1;
        bool oky = (gy >= 0) & (gy < H0);
        float v0 = (oky & (gx0 >= 0) & (gx0 < W0)) ? xb[gy * W0 + gx0] : 0.f;
        float v1 = (oky & (gx1 >= 0) & (gx1 < W0)) ? xb[gy * W0 + gx1] : 0.f;
        *(unsigned int*)&xt[ry][rx] = packh2(v0, v1);
    }
    __syncthreads();

    // conv1+BN1+relu+maxpool2 for the 18x18 halo tile, all 256 threads
    for (int p = tid; p < 18 * 18; p += 256) {
        int pr = p / 18, pc = p % 18;
        int gy = y0 - 1 + pr, gx = x0 - 1 + pc;           // x1 coords
        bool valid = (gy >= 0) & (gy < H1) & (gx >= 0) & (gx < W1);
        float patch[16];
#pragma unroll
        for (int dy = 0; dy < 4; dy++) {
            const unsigned int* rp = (const unsigned int*)&xt[2 * pr + dy][2 * pc];
            union { unsigned int u[2]; _Float16 h[4]; } rv;
            rv.u[0] = rp[0]; rv.u[1] = rp[1];
#pragma unroll
            for (int i = 0; i < 4; i++) patch[dy * 4 + i] = (float)rv.h[i];
        }
        unsigned int u[12];
#pragma unroll
        for (int cp = 0; cp < 12; cp++) {
            float hv[2];
#pragma unroll
            for (int h = 0; h < 2; h++) {
                int c = 2 * cp + h;
                float m4 = -1e30f;
#pragma unroll
                for (int py = 0; py < 2; py++)
#pragma unroll
                    for (int px = 0; px < 2; px++) {
                        float a = blds[c];
#pragma unroll
                        for (int ky = 0; ky < 3; ky++)
#pragma unroll
                            for (int kx = 0; kx < 3; kx++)
                                a = fmaf(patch[(py + ky) * 4 + (px + kx)], wlds[c * 9 + ky * 3 + kx], a);
                        m4 = fmaxf(m4, fmaf(a, alds[c], bflds[c]));
                    }
                hv[h] = valid ? fmaxf(m4, 0.f) : 0.f;
            }
            u[cp] = packh2(hv[0], hv[1]);
        }
        uint4* dst = (uint4*)&x1t[pr][pc][0];
        dst[0] = make_uint4(u[0], u[1], u[2], u[3]);
        dst[1] = make_uint4(u[4], u[5], u[6], u[7]);
        dst[2] = make_uint4(u[8], u[9], u[10], u[11]);
        dst[3] = make_uint4(0, 0, 0, 0);                  // pad ic 24..31
    }
    __syncthreads();

    // MFMA implicit GEMM: wave w -> out rows 4w..4w+3; N=48 (3 tiles); K = 9 taps x 32 ic
    const int w = tid >> 6;
    const int lane = tid & 63;
    const int ml = lane & 15;
    const int q = lane >> 4;

    v4f acc[4][3];
#pragma unroll
    for (int mt = 0; mt < 4; mt++)
#pragma unroll
        for (int nt = 0; nt < 3; nt++)
            acc[mt][nt] = (v4f){0.f, 0.f, 0.f, 0.f};

#pragma unroll
    for (int kp = 0; kp < 9; kp++) {
        const int ky = kp / 3, kx = kp % 3;
        v8h B0 = *(const v8h*)&Blds[((kp * 3 + 0) * 64 + lane) * 8];
        v8h B1 = *(const v8h*)&Blds[((kp * 3 + 1) * 64 + lane) * 8];
        v8h B2 = *(const v8h*)&Blds[((kp * 3 + 2) * 64 + lane) * 8];
#pragma unroll
        for (int mt = 0; mt < 4; mt++) {
            const int r = 4 * w + mt;
            v8h a = *(const v8h*)&x1t[r + ky][ml + kx][q * 8];
            acc[mt][0] = __builtin_amdgcn_mfma_f32_16x16x32_f16(a, B0, acc[mt][0], 0, 0, 0);
            acc[mt][1] = __builtin_amdgcn_mfma_f32_16x16x32_f16(a, B1, acc[mt][1], 0, 0, 0);
            acc[mt][2] = __builtin_amdgcn_mfma_f32_16x16x32_f16(a, B2, acc[mt][2], 0, 0, 0);
        }
    }

    // ---- epilogue: stats + pooled pre-BN max ----
    // D layout per MFMA: pixel-col = q*4+rg, oc = nt*16+ml; rows = 4w+mt.
#pragma unroll
    for (int nt = 0; nt < 3; nt++) {
        int oc = nt * 16 + ml;
        float bias = b2[oc];
        float z[4][4];
        float sv = 0.f, qv = 0.f;
#pragma unroll
        for (int mt = 0; mt < 4; mt++)
#pragma unroll
            for (int rg = 0; rg < 4; rg++) {
                float val = acc[mt][nt][rg] + bias;
                z[mt][rg] = val;
                sv += val;
                qv = fmaf(val, val, qv);
            }
        sv += __shfl_xor(sv, 16, 64); qv += __shfl_xor(qv, 16, 64);
        sv += __shfl_xor(sv, 32, 64); qv += __shfl_xor(qv, 32, 64);
        if (q == 0) { atomicAdd(&sred[oc], sv); atomicAdd(&sred[C2 + oc], qv); }

#pragma unroll
        for (int mtp = 0; mtp < 2; mtp++) {
            int pr = (y0 >> 1) + 2 * w + mtp;
#pragma unroll
            for (int jj = 0; jj < 2; jj++) {
                float m = fmaxf(fmaxf(z[2 * mtp][2 * jj], z[2 * mtp][2 * jj + 1]),
                                fmaxf(z[2 * mtp + 1][2 * jj], z[2 * mtp + 1][2 * jj + 1]));
                int pc = (x0 >> 1) + 2 * q + jj;
                pool[((b * C2 + oc) * H2 + pr) * W2 + pc] = m;
            }
        }
    }
    __syncthreads();
    if (tid < 2 * C2) {
        int cp = (blockIdx.x + 7 * blockIdx.y + 49 * blockIdx.z) & 7;
        atomicAdd(&stats[cp * 2 * C2 + tid], sred[tid]);
    }
}

// ---------------- finalize BN2 coeffs ----------------
__global__ void k_fin2(const float* __restrict__ g, const float* __restrict__ bb, float* __restrict__ ws)
{
    int c = threadIdx.x;
    if (c >= C2) return;
    float s = 0.f, q = 0.f;
    for (int i = 0; i < 8; i++) {
        s += ws[WS_STATS2 + i * 2 * C2 + c];
        q += ws[WS_STATS2 + i * 2 * C2 + C2 + c];
    }
    const float N = (float)(NB * H1 * W1);
    float m = s / N;
    float v = q / N - m * m;
    float a = g[c] / sqrtf(v + EPSV);
    ws[WS_COEF2 + c] = a;
    ws[WS_COEF2 + C2 + c] = bb[c] - m * a;
}

// ---------------- fconv einsum (48x64 GEMM, K=150528) with fused BN2 affine + relu ----------------
#define KC 512
#define KSUB 128
__global__ __launch_bounds__(256) void k_fconv(
    const float* __restrict__ pool, const float* __restrict__ coef2,
    const float* __restrict__ fw, float* __restrict__ feat)
{
    __shared__ float fwt[C2][KSUB + 1];
    __shared__ float x2t[NB][KSUB + 1];
    __shared__ float csh[2 * C2];
    if (threadIdx.x < 2 * C2) csh[threadIdx.x] = coef2[threadIdx.x];
    int k0 = blockIdx.x * KC;
    int i = threadIdx.x / 16, j = threadIdx.x % 16;
    float acc[3][4] = {{0.f}};
    for (int sub = 0; sub < KC / KSUB; sub++) {
        int kb = k0 + sub * KSUB;
        __syncthreads();
        for (int li = threadIdx.x; li < C2 * KSUB; li += 256) {
            int o = li / KSUB, k = li % KSUB;
            fwt[o][k] = fw[o * 150528 + kb + k];
        }
        for (int li = threadIdx.x; li < NB * KSUB; li += 256) {
            int b = li / KSUB, k = li % KSUB;
            int kk = kb + k;
            int c = kk / (H2 * W2);
            float v = pool[b * 150528 + kk];
            x2t[b][k] = fmaxf(fmaf(v, csh[c], csh[C2 + c]), 0.f);   // BN2 affine + relu
        }
        __syncthreads();
        for (int k = 0; k < KSUB; k++) {
            float fa[3], xv[4];
#pragma unroll
            for (int c = 0; c < 3; c++) fa[c] = fwt[i + 16 * c][k];
#pragma unroll
            for (int d = 0; d < 4; d++) xv[d] = x2t[j + 16 * d][k];
#pragma unroll
            for (int c = 0; c < 3; c++)
#pragma unroll
                for (int d = 0; d < 4; d++)
                    acc[c][d] = fmaf(fa[c], xv[d], acc[c][d]);
        }
    }
#pragma unroll
    for (int c = 0; c < 3; c++)
#pragma unroll
        for (int d = 0; d < 4; d++)
            atomicAdd(&feat[(j + 16 * d) * C2 + (i + 16 * c)], acc[c][d]);
}

// ---------------- linear head -> theta4 (d_out tail) ----------------
__global__ void k_head(const float* __restrict__ feat, const float* __restrict__ fcb,
                       const float* __restrict__ l1w, const float* __restrict__ l1b,
                       const float* __restrict__ l2w, const float* __restrict__ l2b,
                       float* __restrict__ tail)
{
    int b = threadIdx.x;
    if (b >= NB) return;
    float f[C2];
    for (int o = 0; o < C2; o++) f[o] = feat[b * C2 + o] + fcb[o];
    float h[24];
    for (int jj = 0; jj < 24; jj++) {
        float a = l1b[jj];
        for (int o = 0; o < C2; o++) a = fmaf(f[o], l1w[jj * C2 + o], a);
        h[jj] = fmaxf(a, 0.f);
    }
    for (int ii = 0; ii < 4; ii++) {
        float a = l2b[ii];
        for (int jj = 0; jj < 24; jj++) a = fmaf(h[jj], l2w[ii * 24 + jj], a);
        tail[ii * NB + b] = a;
    }
}

// ---------------- affine grid + bilinear grid_sample ----------------
__global__ __launch_bounds__(256) void k_sample(
    const float* __restrict__ x, const float* __restrict__ tail, float* __restrict__ out)
{
    int b = blockIdx.y;
    int idx = blockIdx.x * 256 + threadIdx.x;
    int i = idx / W0, j = idx % W0;
    float tx = tail[0 * NB + b], ty = tail[1 * NB + b];
    float sc = tail[2 * NB + b], an = tail[3 * NB + b];
    float cc = cosf(an), ss = sinf(an);
    float t00 = sc * cc, t01 = -sc * ss, t10 = sc * ss, t11 = sc * cc;
    float xs = (2.f * (float)j + 1.f) / (float)W0 - 1.f;
    float ys = (2.f * (float)i + 1.f) / (float)H0 - 1.f;
    float gx = t00 * xs + t01 * ys + tx;
    float gy = t10 * xs + t11 * ys + ty;
    float ix = ((gx + 1.f) * (float)W0 - 1.f) * 0.5f;
    float iy = ((gy + 1.f) * (float)H0 - 1.f) * 0.5f;
    float x0 = floorf(ix), y0 = floorf(iy);
    float x1f = x0 + 1.f, y1f = y0 + 1.f;
    float wx1 = ix - x0, wx0 = 1.f - wx1;
    float wy1 = iy - y0, wy0 = 1.f - wy1;
    const float* xb = x + b * (H0 * W0);
    auto tap = [&](float xf, float yf, float wgt) -> float {
        bool valid = (xf >= 0.f) & (xf < (float)W0) & (yf >= 0.f) & (yf < (float)H0);
        int xi = (int)fminf(fmaxf(xf, 0.f), (float)(W0 - 1));
        int yi = (int)fminf(fmaxf(yf, 0.f), (float)(H0 - 1));
        return valid ? xb[yi * W0 + xi] * wgt : 0.f;
    };
    float o = tap(x0, y0, wx0 * wy0) + tap(x1f, y0, wx1 * wy0)
            + tap(x0, y1f, wx0 * wy1) + tap(x1f, y1f, wx1 * wy1);
    out[(b * H0 + i) * W0 + j] = o;
}

extern "C" void kernel_launch(void* const* d_in, const int* in_sizes, int n_in,
                              void* d_out, int out_size, void* d_ws, size_t ws_size,
                              hipStream_t stream)
{
    const float* x    = (const float*)d_in[0];
    const float* c1w  = (const float*)d_in[1];
    const float* c1b  = (const float*)d_in[2];
    const float* bn1g = (const float*)d_in[3];
    const float* bn1b = (const float*)d_in[4];
    const float* c2w  = (const float*)d_in[5];
    const float* c2b  = (const float*)d_in[6];
    const float* bn2g = (const float*)d_in[7];
    const float* bn2b = (const float*)d_in[8];
    const float* fw   = (const float*)d_in[9];
    const float* fcb  = (const float*)d_in[10];
    const float* l1w  = (const float*)d_in[11];
    const float* l1b  = (const float*)d_in[12];
    const float* l2w  = (const float*)d_in[13];
    const float* l2b  = (const float*)d_in[14];
    float* ws  = (float*)d_ws;
    float* out = (float*)d_out;

    // zero stats/coef/feat region (17.5 KB)
    hipMemsetAsync(ws, 0, WS_B2 * sizeof(float), stream);

    k_prep<<<dim3(54), 256, 0, stream>>>(c2w, (_Float16*)(ws + WS_B2));
    k_conv1_stats<<<dim3(1024), 256, 0, stream>>>(x, c1w, c1b, ws);
    k_fin1<<<1, 64, 0, stream>>>(bn1g, bn1b, ws);
    k_conv2_fused<<<dim3(7, 7, 64), 256, 0, stream>>>(
        x, c1w, c1b, ws + WS_COEF1, (const _Float16*)(ws + WS_B2),
        c2b, ws + WS_STATS2, ws + WS_X2);
    k_fin2<<<1, 64, 0, stream>>>(bn2g, bn2b, ws);
    k_fconv<<<dim3(150528 / KC), 256, 0, stream>>>(ws + WS_X2, ws + WS_COEF2, fw, ws + WS_FEAT);
    k_head<<<1, 64, 0, stream>>>(ws + WS_FEAT, fcb, l1w, l1b, l2w, l2b, out + OUT0_ELEMS);
    k_sample<<<dim3(196, 64), 256, 0, stream>>>(x, out + OUT0_ELEMS, out);
}

// Round 7
// 333.936 us; speedup vs baseline: 1.3219x; 1.3219x over previous
//
#include <hip/hip_runtime.h>
#include <hip/hip_bf16.h>

#define NB 64
#define H0 224
#define W0 224
#define C1 24
#define C2 48
#define H1 112
#define W1 112
#define H2 56
#define W2 56
#define EPSV 1e-5f

// ws layout (float offsets) — total ~38.6 MB (proven safe)
#define WS_STATS1   0                       // 8 x (24+24) = 384
#define WS_STATS2   432                     // 8 x (48+48) = 768
#define WS_FEAT     1296                    // 64*48 = 3072
#define WS_B2       4368                    // 13824 fp16 = 6912 float slots (wave-linear w2 frags)
#define WS_X2       11280                   // fp32, pooled PRE-BN conv2 max, 64*48*56*56
#define OUT0_ELEMS  (NB*H0*W0)

typedef _Float16 v8h __attribute__((ext_vector_type(8)));   // 8 fp16 (4 VGPRs)
typedef float    v4f __attribute__((ext_vector_type(4)));   // MFMA acc

static __device__ __forceinline__ unsigned short f2h(float v) {
    _Float16 h = (_Float16)v;
    unsigned short us;
    __builtin_memcpy(&us, &h, 2);
    return us;
}

// ---------------- K0: zero stats/feat region + prep w2 -> wave-linear fp16 frags ----------------
// bpp[(g*64 + l)*8 + e], g=kp*3+nt, holds w2[oc=nt*16+(l&15)][ic=(l>>4)*8+e][kp] (0 for ic>=24).
__global__ __launch_bounds__(256) void k_init(const float* __restrict__ w2, float* __restrict__ ws)
{
    int t = blockIdx.x * 256 + threadIdx.x;   // grid 54*256 = 13824
    if (t < WS_B2) ws[t] = 0.f;
    if (t < 13824) {
        int e = t & 7;
        int l = (t >> 3) & 63;
        int g = t >> 9;
        int q = l >> 4, ml = l & 15;
        int kp = g / 3, nt = g % 3;
        int ic = q * 8 + e;
        int oc = nt * 16 + ml;
        float v = (ic < C1) ? w2[(oc * C1 + ic) * 9 + kp] : 0.f;
        ((_Float16*)(ws + WS_B2))[t] = (_Float16)v;
    }
}

// ---------------- K1: conv1 -> per-channel sum/sumsq (BN1 stats), full fp32 ----------------
__global__ __launch_bounds__(256) void k_conv1_stats(
    const float* __restrict__ x, const float* __restrict__ w1, const float* __restrict__ b1,
    float* __restrict__ ws)
{
    float s[C1], q[C1];
#pragma unroll
    for (int c = 0; c < C1; c++) { s[c] = 0.f; q[c] = 0.f; }
    const int NT = gridDim.x * 256;
    const int total = NB * H0 * W0;
    for (int p = blockIdx.x * 256 + threadIdx.x; p < total; p += NT) {
        int b = p / (H0 * W0);
        int r = p % (H0 * W0);
        int y = r / W0;
        int xx = r % W0;
        const float* xb = x + b * (H0 * W0);
        float patch[9];
#pragma unroll
        for (int dy = 0; dy < 3; dy++)
#pragma unroll
            for (int dx = 0; dx < 3; dx++) {
                int yy = y + dy - 1, xc = xx + dx - 1;
                bool ok = (yy >= 0) & (yy < H0) & (xc >= 0) & (xc < W0);
                patch[dy * 3 + dx] = ok ? xb[yy * W0 + xc] : 0.f;
            }
#pragma unroll
        for (int c = 0; c < C1; c++) {
            const float* wp = w1 + c * 9;
            float a = b1[c];
#pragma unroll
            for (int k = 0; k < 9; k++) a = fmaf(patch[k], wp[k], a);
            s[c] += a;
            q[c] = fmaf(a, a, q[c]);
        }
    }
#pragma unroll
    for (int c = 0; c < C1; c++) {
#pragma unroll
        for (int off = 32; off > 0; off >>= 1) {
            s[c] += __shfl_down(s[c], off, 64);
            q[c] += __shfl_down(q[c], off, 64);
        }
    }
    __shared__ float sred[2 * C1];
    if (threadIdx.x < 2 * C1) sred[threadIdx.x] = 0.f;
    __syncthreads();
    if ((threadIdx.x & 63) == 0) {
#pragma unroll
        for (int c = 0; c < C1; c++) {
            atomicAdd(&sred[c], s[c]);
            atomicAdd(&sred[C1 + c], q[c]);
        }
    }
    __syncthreads();
    if (threadIdx.x < 2 * C1) {
        atomicAdd(&ws[WS_STATS1 + (blockIdx.x & 7) * 2 * C1 + threadIdx.x], sred[threadIdx.x]);
    }
}

// ---------------- Fused single pass: inline-BN1 + conv1(recompute)+relu+pool -> conv2 MFMA ----------------
// Emits BN2 stats AND pooled PRE-BN max (a2>0 so maxpool commutes with BN2 affine+relu).
// Tile: 8x16 conv2 outputs (R5-proven). Grid (7, 14, 64).
__global__ __launch_bounds__(256, 2) void k_conv2_fused(
    const float* __restrict__ x, const float* __restrict__ w1, const float* __restrict__ b1,
    const float* __restrict__ g1, const float* __restrict__ bb1,
    const _Float16* __restrict__ bpp, const float* __restrict__ b2,
    float* __restrict__ ws, float* __restrict__ pool)
{
    __shared__ float xt[22][38];                             // raw x tile (fp32, R5-proven)
    __shared__ __align__(16) _Float16 x1t[10][18][32];       // x1 tile, ch-last, ic pad 32 (11520 B)
    __shared__ __align__(16) _Float16 Blds[13824];           // w2 frags, wave-linear (27648 B)
    __shared__ float wlds[C1 * 9];
    __shared__ float blds[C1], alds[C1], bflds[C1];
    __shared__ float sred[2 * C2];

    const int tid = threadIdx.x;
    const int b = blockIdx.z;
    const int y0 = blockIdx.y * 8;
    const int x0 = blockIdx.x * 16;
    const float* xb = x + b * (H0 * W0);

    // stage B fragments into LDS (latency hidden under conv1 phase)
    for (int li = tid; li < 13824 / 8; li += 256)
        ((uint4*)Blds)[li] = ((const uint4*)bpp)[li];

    if (tid < C1 * 9) wlds[tid] = w1[tid];
    if (tid < C1) {
        // inline BN1 finalize (replicated per block; stats1 complete before this kernel)
        float s = 0.f, q = 0.f;
#pragma unroll
        for (int i = 0; i < 8; i++) {
            s += ws[WS_STATS1 + i * 2 * C1 + tid];
            q += ws[WS_STATS1 + i * 2 * C1 + C1 + tid];
        }
        const float N = (float)(NB * H0 * W0);
        float m = s / N;
        float v = q / N - m * m;
        float a = g1[tid] / sqrtf(v + EPSV);
        blds[tid] = b1[tid];
        alds[tid] = a;
        bflds[tid] = bb1[tid] - m * a;
    }
    if (tid < 2 * C2) sred[tid] = 0.f;

    // stage raw x tile: rows 2*y0-3 .. +21, cols 2*x0-3 .. +34 (22x38)
    const int oy0 = 2 * y0 - 3, ox0 = 2 * x0 - 3;
    for (int li = tid; li < 22 * 38; li += 256) {
        int ry = li / 38, rx = li % 38;
        int gy = oy0 + ry, gx = ox0 + rx;
        bool ok = (gy >= 0) & (gy < H0) & (gx >= 0) & (gx < W0);
        xt[ry][rx] = ok ? xb[gy * W0 + gx] : 0.f;
    }
    __syncthreads();

    // conv1+BN1+relu+pool: one thread per x1-tile position, all 24 ic (R5-proven codegen)
    if (tid < 180) {
        int pr = tid / 18, pc = tid % 18;
        int gy = y0 - 1 + pr, gx = x0 - 1 + pc;           // x1 coords
        bool valid = (gy >= 0) & (gy < H1) & (gx >= 0) & (gx < W1);
        float patch[16];
#pragma unroll
        for (int dy = 0; dy < 4; dy++)
#pragma unroll
            for (int dx = 0; dx < 4; dx++)
                patch[dy * 4 + dx] = xt[2 * pr + dy][2 * pc + dx];
        unsigned int* dst = (unsigned int*)&x1t[pr][pc][0];
#pragma unroll
        for (int cp = 0; cp < 12; cp++) {
            unsigned int pk = 0;
#pragma unroll
            for (int h = 0; h < 2; h++) {
                int c = 2 * cp + h;
                float m4 = -1e30f;
#pragma unroll
                for (int py = 0; py < 2; py++)
#pragma unroll
                    for (int px = 0; px < 2; px++) {
                        float a = blds[c];
#pragma unroll
                        for (int ky = 0; ky < 3; ky++)
#pragma unroll
                            for (int kx = 0; kx < 3; kx++)
                                a = fmaf(patch[(py + ky) * 4 + (px + kx)], wlds[c * 9 + ky * 3 + kx], a);
                        m4 = fmaxf(m4, fmaf(a, alds[c], bflds[c]));
                    }
                float v = valid ? fmaxf(m4, 0.f) : 0.f;
                pk |= ((unsigned int)f2h(v)) << (16 * h);
            }
            dst[cp] = pk;
        }
        dst[12] = 0; dst[13] = 0; dst[14] = 0; dst[15] = 0;   // pad ic 24..31
    }
    __syncthreads();

    // MFMA implicit GEMM: wave w -> out rows {2w, 2w+1}; N=48 (3 tiles); K = 9 taps x 32 ic
    const int w = tid >> 6;
    const int lane = tid & 63;
    const int ml = lane & 15;
    const int q = lane >> 4;

    v4f acc[2][3];
#pragma unroll
    for (int mt = 0; mt < 2; mt++)
#pragma unroll
        for (int nt = 0; nt < 3; nt++)
            acc[mt][nt] = (v4f){0.f, 0.f, 0.f, 0.f};

#pragma unroll
    for (int kp = 0; kp < 9; kp++) {
        const int ky = kp / 3, kx = kp % 3;
        v8h B0 = *(const v8h*)&Blds[((kp * 3 + 0) * 64 + lane) * 8];
        v8h B1 = *(const v8h*)&Blds[((kp * 3 + 1) * 64 + lane) * 8];
        v8h B2 = *(const v8h*)&Blds[((kp * 3 + 2) * 64 + lane) * 8];
#pragma unroll
        for (int mt = 0; mt < 2; mt++) {
            const int r = 2 * w + mt;
            v8h a = *(const v8h*)&x1t[r + ky][ml + kx][q * 8];
            acc[mt][0] = __builtin_amdgcn_mfma_f32_16x16x32_f16(a, B0, acc[mt][0], 0, 0, 0);
            acc[mt][1] = __builtin_amdgcn_mfma_f32_16x16x32_f16(a, B1, acc[mt][1], 0, 0, 0);
            acc[mt][2] = __builtin_amdgcn_mfma_f32_16x16x32_f16(a, B2, acc[mt][2], 0, 0, 0);
        }
    }

    // ---- epilogue: stats + pooled pre-BN max (R5-proven) ----
#pragma unroll
    for (int nt = 0; nt < 3; nt++) {
        int oc = nt * 16 + ml;
        float bias = b2[oc];
        float z[2][4];
        float sv = 0.f, qv = 0.f;
#pragma unroll
        for (int mt = 0; mt < 2; mt++)
#pragma unroll
            for (int rg = 0; rg < 4; rg++) {
                float val = acc[mt][nt][rg] + bias;
                z[mt][rg] = val;
                sv += val;
                qv = fmaf(val, val, qv);
            }
        sv += __shfl_xor(sv, 16, 64); qv += __shfl_xor(qv, 16, 64);
        sv += __shfl_xor(sv, 32, 64); qv += __shfl_xor(qv, 32, 64);
        if (q == 0) { atomicAdd(&sred[oc], sv); atomicAdd(&sred[C2 + oc], qv); }

        int py = (y0 >> 1) + w;
#pragma unroll
        for (int j = 0; j < 2; j++) {
            float m = fmaxf(fmaxf(z[0][2 * j], z[0][2 * j + 1]),
                            fmaxf(z[1][2 * j], z[1][2 * j + 1]));
            int px = (x0 >> 1) + q * 2 + j;
            pool[((b * C2 + oc) * H2 + py) * W2 + px] = m;
        }
    }
    __syncthreads();
    if (tid < 2 * C2) {
        int cp = (blockIdx.x + 7 * blockIdx.y + 31 * blockIdx.z) & 7;
        atomicAdd(&ws[WS_STATS2 + cp * 2 * C2 + tid], sred[tid]);
    }
}

// ---------------- fconv (48x64 GEMM, K=150528) with inline-fin2 + fused BN2 affine + relu ----------------
#define KC 512
#define KSUB 128
__global__ __launch_bounds__(256) void k_fconv(
    const float* __restrict__ pool, const float* __restrict__ ws,
    const float* __restrict__ g2, const float* __restrict__ bb2,
    const float* __restrict__ fw, float* __restrict__ feat)
{
    __shared__ float fwt[C2][KSUB + 1];
    __shared__ float x2t[NB][KSUB + 1];
    __shared__ float csh[2 * C2];
    if (threadIdx.x < C2) {
        // inline BN2 finalize (replicated per block; stats2 complete before this kernel)
        int c = threadIdx.x;
        float s = 0.f, q = 0.f;
#pragma unroll
        for (int i = 0; i < 8; i++) {
            s += ws[WS_STATS2 + i * 2 * C2 + c];
            q += ws[WS_STATS2 + i * 2 * C2 + C2 + c];
        }
        const float N = (float)(NB * H1 * W1);
        float m = s / N;
        float v = q / N - m * m;
        float a = g2[c] / sqrtf(v + EPSV);
        csh[c] = a;
        csh[C2 + c] = bb2[c] - m * a;
    }
    int k0 = blockIdx.x * KC;
    int i = threadIdx.x / 16, j = threadIdx.x % 16;
    float acc[3][4] = {{0.f}};
    for (int sub = 0; sub < KC / KSUB; sub++) {
        int kb = k0 + sub * KSUB;
        __syncthreads();
        for (int li = threadIdx.x; li < C2 * KSUB; li += 256) {
            int o = li / KSUB, k = li % KSUB;
            fwt[o][k] = fw[o * 150528 + kb + k];
        }
        for (int li = threadIdx.x; li < NB * KSUB; li += 256) {
            int b = li / KSUB, k = li % KSUB;
            int kk = kb + k;
            int c = kk / (H2 * W2);
            float v = pool[b * 150528 + kk];
            x2t[b][k] = fmaxf(fmaf(v, csh[c], csh[C2 + c]), 0.f);   // BN2 affine + relu
        }
        __syncthreads();
        for (int k = 0; k < KSUB; k++) {
            float fa[3], xv[4];
#pragma unroll
            for (int c = 0; c < 3; c++) fa[c] = fwt[i + 16 * c][k];
#pragma unroll
            for (int d = 0; d < 4; d++) xv[d] = x2t[j + 16 * d][k];
#pragma unroll
            for (int c = 0; c < 3; c++)
#pragma unroll
                for (int d = 0; d < 4; d++)
                    acc[c][d] = fmaf(fa[c], xv[d], acc[c][d]);
        }
    }
#pragma unroll
    for (int c = 0; c < 3; c++)
#pragma unroll
        for (int d = 0; d < 4; d++)
            atomicAdd(&feat[(j + 16 * d) * C2 + (i + 16 * c)], acc[c][d]);
}

// ---------------- sample with inline head: theta4 + affine grid + bilinear grid_sample ----------------
__global__ __launch_bounds__(256) void k_sample(
    const float* __restrict__ x, const float* __restrict__ feat, const float* __restrict__ fcb,
    const float* __restrict__ l1w, const float* __restrict__ l1b,
    const float* __restrict__ l2w, const float* __restrict__ l2b,
    float* __restrict__ out)
{
    __shared__ float hsh[24];
    __shared__ float th[4];
    int b = blockIdx.y;
    int tid = threadIdx.x;
    if (tid < 24) {
        float a = l1b[tid];
        for (int o = 0; o < C2; o++)
            a = fmaf(feat[b * C2 + o] + fcb[o], l1w[tid * C2 + o], a);
        hsh[tid] = fmaxf(a, 0.f);
    }
    __syncthreads();
    if (tid < 4) {
        float a = l2b[tid];
        for (int jj = 0; jj < 24; jj++) a = fmaf(hsh[jj], l2w[tid * 24 + jj], a);
        th[tid] = a;
        if (blockIdx.x == 0) out[OUT0_ELEMS + tid * NB + b] = a;   // tx, ty, scale, angle outputs
    }
    __syncthreads();

    int idx = blockIdx.x * 256 + tid;
    int i = idx / W0, j = idx % W0;
    float tx = th[0], ty = th[1], sc = th[2], an = th[3];
    float cc = cosf(an), ss = sinf(an);
    float t00 = sc * cc, t01 = -sc * ss, t10 = sc * ss, t11 = sc * cc;
    float xs = (2.f * (float)j + 1.f) / (float)W0 - 1.f;
    float ys = (2.f * (float)i + 1.f) / (float)H0 - 1.f;
    float gx = t00 * xs + t01 * ys + tx;
    float gy = t10 * xs + t11 * ys + ty;
    float ix = ((gx + 1.f) * (float)W0 - 1.f) * 0.5f;
    float iy = ((gy + 1.f) * (float)H0 - 1.f) * 0.5f;
    float x0 = floorf(ix), y0 = floorf(iy);
    float x1f = x0 + 1.f, y1f = y0 + 1.f;
    float wx1 = ix - x0, wx0 = 1.f - wx1;
    float wy1 = iy - y0, wy0 = 1.f - wy1;
    const float* xb = x + b * (H0 * W0);
    auto tap = [&](float xf, float yf, float wgt) -> float {
        bool valid = (xf >= 0.f) & (xf < (float)W0) & (yf >= 0.f) & (yf < (float)H0);
        int xi = (int)fminf(fmaxf(xf, 0.f), (float)(W0 - 1));
        int yi = (int)fminf(fmaxf(yf, 0.f), (float)(H0 - 1));
        return valid ? xb[yi * W0 + xi] * wgt : 0.f;
    };
    float o = tap(x0, y0, wx0 * wy0) + tap(x1f, y0, wx1 * wy0)
            + tap(x0, y1f, wx0 * wy1) + tap(x1f, y1f, wx1 * wy1);
    out[(b * H0 + i) * W0 + j] = o;
}

extern "C" void kernel_launch(void* const* d_in, const int* in_sizes, int n_in,
                              void* d_out, int out_size, void* d_ws, size_t ws_size,
                              hipStream_t stream)
{
    const float* x    = (const float*)d_in[0];
    const float* c1w  = (const float*)d_in[1];
    const float* c1b  = (const float*)d_in[2];
    const float* bn1g = (const float*)d_in[3];
    const float* bn1b = (const float*)d_in[4];
    const float* c2w  = (const float*)d_in[5];
    const float* c2b  = (const float*)d_in[6];
    const float* bn2g = (const float*)d_in[7];
    const float* bn2b = (const float*)d_in[8];
    const float* fw   = (const float*)d_in[9];
    const float* fcb  = (const float*)d_in[10];
    const float* l1w  = (const float*)d_in[11];
    const float* l1b  = (const float*)d_in[12];
    const float* l2w  = (const float*)d_in[13];
    const float* l2b  = (const float*)d_in[14];
    float* ws  = (float*)d_ws;
    float* out = (float*)d_out;

    k_init<<<dim3(54), 256, 0, stream>>>(c2w, ws);
    k_conv1_stats<<<dim3(1024), 256, 0, stream>>>(x, c1w, c1b, ws);
    k_conv2_fused<<<dim3(7, 14, 64), 256, 0, stream>>>(
        x, c1w, c1b, bn1g, bn1b, (const _Float16*)(ws + WS_B2), c2b, ws, ws + WS_X2);
    k_fconv<<<dim3(150528 / KC), 256, 0, stream>>>(ws + WS_X2, ws, bn2g, bn2b, fw, ws + WS_FEAT);
    k_sample<<<dim3(196, 64), 256, 0, stream>>>(x, ws + WS_FEAT, fcb, l1w, l1b, l2w, l2b, out);
}